// Round 1
// baseline (433.616 us; speedup 1.0000x reference)
//
#include <hip/hip_runtime.h>
#include <hip/hip_bf16.h>

#define FEATURES 1024
#define NREFL 4

// Kernel 1: normalize the 4 Householder vectors into workspace.
// grid = 4 blocks (one per reflection), 256 threads; each thread owns 4 elems (float4).
__global__ __launch_bounds__(256) void hh_normalize(const float* __restrict__ vec,
                                                    float* __restrict__ w) {
    __shared__ float red[4];
    const int i = blockIdx.x;      // reflection index
    const int t = threadIdx.x;     // 0..255
    const float4 val = *(const float4*)(vec + i * FEATURES + t * 4);
    float s = val.x * val.x + val.y * val.y + val.z * val.z + val.w * val.w;
    // 64-lane wave butterfly reduction
    #pragma unroll
    for (int off = 32; off > 0; off >>= 1) s += __shfl_xor(s, off);
    if ((t & 63) == 0) red[t >> 6] = s;
    __syncthreads();
    const float total = red[0] + red[1] + red[2] + red[3];
    const float inv = 1.0f / sqrtf(total);
    float4 o;
    o.x = val.x * inv; o.y = val.y * inv; o.z = val.z * inv; o.w = val.w * inv;
    *(float4*)(w + i * FEATURES + t * 4) = o;
}

// Kernel 2: apply out = x * H0 * H1 * H2 * H3 row-wise.
// One 64-lane wave per row (grid-stride). Lane l owns elements {c*256 + 4l .. +3}
// for c=0..3 (fully coalesced float4 access). Normalized vectors held in VGPRs.
__global__ __launch_bounds__(256) void hh_apply(const float* __restrict__ x,
                                                const float* __restrict__ w,
                                                float* __restrict__ out,
                                                int batch) {
    const int lane   = threadIdx.x & 63;
    const int wave   = blockIdx.x * (blockDim.x >> 6) + (threadIdx.x >> 6);
    const int nwaves = gridDim.x * (blockDim.x >> 6);

    // Load all 4 normalized vectors into registers: v[refl][chunk]
    float4 v[NREFL][4];
    #pragma unroll
    for (int i = 0; i < NREFL; ++i)
        #pragma unroll
        for (int c = 0; c < 4; ++c)
            v[i][c] = *(const float4*)(w + i * FEATURES + c * 256 + lane * 4);

    for (int row = wave; row < batch; row += nwaves) {
        const float* xr = x + (size_t)row * FEATURES;
        float4 y[4];
        #pragma unroll
        for (int c = 0; c < 4; ++c)
            y[c] = *(const float4*)(xr + c * 256 + lane * 4);

        #pragma unroll
        for (int i = 0; i < NREFL; ++i) {
            // d = dot(y, v_i) across the full row
            float d = 0.0f;
            #pragma unroll
            for (int c = 0; c < 4; ++c)
                d += y[c].x * v[i][c].x + y[c].y * v[i][c].y +
                     y[c].z * v[i][c].z + y[c].w * v[i][c].w;
            #pragma unroll
            for (int off = 32; off > 0; off >>= 1) d += __shfl_xor(d, off);
            d *= 2.0f;
            // y -= 2*d * v_i
            #pragma unroll
            for (int c = 0; c < 4; ++c) {
                y[c].x -= d * v[i][c].x;
                y[c].y -= d * v[i][c].y;
                y[c].z -= d * v[i][c].z;
                y[c].w -= d * v[i][c].w;
            }
        }

        float* orow = out + (size_t)row * FEATURES;
        #pragma unroll
        for (int c = 0; c < 4; ++c)
            *(float4*)(orow + c * 256 + lane * 4) = y[c];
    }
}

extern "C" void kernel_launch(void* const* d_in, const int* in_sizes, int n_in,
                              void* d_out, int out_size, void* d_ws, size_t ws_size,
                              hipStream_t stream) {
    const float* x   = (const float*)d_in[0];
    const float* vec = (const float*)d_in[1];
    float* out = (float*)d_out;
    float* wv  = (float*)d_ws;  // 4*1024 floats = 16 KB of scratch

    const int batch = in_sizes[0] / FEATURES;

    hh_normalize<<<NREFL, 256, 0, stream>>>(vec, wv);

    // 2048 blocks * 4 waves = 8192 waves; each wave handles batch/8192 = 8 rows.
    hh_apply<<<2048, 256, 0, stream>>>(x, wv, out, batch);
}